// Round 2
// baseline (697.753 us; speedup 1.0000x reference)
//
#include <hip/hip_runtime.h>
#include <hip/hip_bf16.h>

#define B 8
#define T 1024
#define C 128
#define H 8
#define E 16

// ---------------- Kernel 1: LayerNorm + QKV projection ----------------
// one block of 128 threads per (b,t) row
__global__ __launch_bounds__(C) void k_ln_qkv(
    const float* __restrict__ x,
    const float* __restrict__ Wq,
    const float* __restrict__ Wk,
    const float* __restrict__ Wv,
    const float* __restrict__ g,
    const float* __restrict__ bb,
    float* __restrict__ q, float* __restrict__ k, float* __restrict__ v)
{
    const int row = blockIdx.x;       // b*T + t
    const int c = threadIdx.x;        // 0..127
    __shared__ float s1[C], s2[C], ln[C];
    float xv = x[(size_t)row * C + c];
    s1[c] = xv; s2[c] = xv * xv;
    __syncthreads();
    for (int st = C / 2; st > 0; st >>= 1) {
        if (c < st) { s1[c] += s1[c + st]; s2[c] += s2[c + st]; }
        __syncthreads();
    }
    float mu  = s1[0] * (1.f / C);
    float var = s2[0] * (1.f / C) - mu * mu;
    float lnv = (xv - mu) * rsqrtf(var + 1e-5f) * g[c] + bb[c];
    ln[c] = lnv;
    __syncthreads();

    float aq = 0.f, ak = 0.f, av = 0.f;
    #pragma unroll 8
    for (int i = 0; i < C; ++i) {
        float l = ln[i];
        aq = fmaf(l, Wq[i * C + c], aq);
        ak = fmaf(l, Wk[i * C + c], ak);
        av = fmaf(l, Wv[i * C + c], av);
    }
    const int b = row >> 10, t = row & (T - 1);
    const int h = c >> 4,   e = c & (E - 1);
    size_t idx = (((size_t)(b * H + h)) * T + t) * E + e;   // [B,H,T,E]
    q[idx] = aq; k[idx] = ak; v[idx] = av;
}

// ---------------- Kernel 2: fused rel-pos causal attention ----------------
// one wave (64 lanes) per (b,h,t); 4 waves per block share (b,h), consecutive t
__global__ __launch_bounds__(256) void k_attn(
    const float* __restrict__ q, const float* __restrict__ k,
    const float* __restrict__ v, const float* __restrict__ wpe,
    float* __restrict__ y)
{
    const int gw   = blockIdx.x * 4 + (threadIdx.x >> 6);
    const int lane = threadIdx.x & 63;
    const int t    = gw & (T - 1);
    const int bh   = gw >> 10;          // b*H + h
    const int h    = bh & (H - 1);

    const float4* qp = reinterpret_cast<const float4*>(q + ((size_t)bh * T + t) * E);
    float4 q0 = qp[0], q1 = qp[1], q2 = qp[2], q3 = qp[3];

    float m = -INFINITY, l = 0.f;
    float4 A0 = {0,0,0,0}, A1 = {0,0,0,0}, A2 = {0,0,0,0}, A3 = {0,0,0,0};

    for (int s0 = 0; s0 <= t; s0 += 64) {
        int s = s0 + lane;
        if (s <= t) {
            const float4* kp = reinterpret_cast<const float4*>(k + ((size_t)bh * T + s) * E);
            float4 k0 = kp[0], k1 = kp[1], k2 = kp[2], k3 = kp[3];
            int d = t - s;                                   // 0..1023
            const float4* wp = reinterpret_cast<const float4*>(wpe + (size_t)d * C + h * E);
            float4 r0 = wp[0], r1 = wp[1], r2 = wp[2], r3 = wp[3];
            // score = q . (k + wpe[t-s])  (rel term folds into key)
            float sc;
            sc  = q0.x * (k0.x + r0.x) + q0.y * (k0.y + r0.y)
                + q0.z * (k0.z + r0.z) + q0.w * (k0.w + r0.w)
                + q1.x * (k1.x + r1.x) + q1.y * (k1.y + r1.y)
                + q1.z * (k1.z + r1.z) + q1.w * (k1.w + r1.w)
                + q2.x * (k2.x + r2.x) + q2.y * (k2.y + r2.y)
                + q2.z * (k2.z + r2.z) + q2.w * (k2.w + r2.w)
                + q3.x * (k3.x + r3.x) + q3.y * (k3.y + r3.y)
                + q3.z * (k3.z + r3.z) + q3.w * (k3.w + r3.w);
            sc *= 0.25f;   // 1/sqrt(E)

            const float4* vp = reinterpret_cast<const float4*>(v + ((size_t)bh * T + s) * E);
            float4 v0 = vp[0], v1 = vp[1], v2 = vp[2], v3 = vp[3];

            float mn = fmaxf(m, sc);
            float f  = __expf(m - mn);     // m=-inf first time -> f=0
            float p  = __expf(sc - mn);
            l = l * f + p;
            A0.x = A0.x * f + p * v0.x; A0.y = A0.y * f + p * v0.y;
            A0.z = A0.z * f + p * v0.z; A0.w = A0.w * f + p * v0.w;
            A1.x = A1.x * f + p * v1.x; A1.y = A1.y * f + p * v1.y;
            A1.z = A1.z * f + p * v1.z; A1.w = A1.w * f + p * v1.w;
            A2.x = A2.x * f + p * v2.x; A2.y = A2.y * f + p * v2.y;
            A2.z = A2.z * f + p * v2.z; A2.w = A2.w * f + p * v2.w;
            A3.x = A3.x * f + p * v3.x; A3.y = A3.y * f + p * v3.y;
            A3.z = A3.z * f + p * v3.z; A3.w = A3.w * f + p * v3.w;
            m = mn;
        }
    }

    // cross-lane merge of 64 partial online-softmax states
    float mg = m;
    #pragma unroll
    for (int off = 32; off; off >>= 1) mg = fmaxf(mg, __shfl_xor(mg, off, 64));
    float f = __expf(m - mg);             // lanes with m=-inf -> f=0 (acc already 0)
    l *= f;
    A0.x *= f; A0.y *= f; A0.z *= f; A0.w *= f;
    A1.x *= f; A1.y *= f; A1.z *= f; A1.w *= f;
    A2.x *= f; A2.y *= f; A2.z *= f; A2.w *= f;
    A3.x *= f; A3.y *= f; A3.z *= f; A3.w *= f;
    #pragma unroll
    for (int off = 32; off; off >>= 1) l += __shfl_xor(l, off, 64);
    #define RED(X) { float _t = (X); _Pragma("unroll") \
        for (int off = 32; off; off >>= 1) _t += __shfl_xor(_t, off, 64); (X) = _t; }
    RED(A0.x) RED(A0.y) RED(A0.z) RED(A0.w)
    RED(A1.x) RED(A1.y) RED(A1.z) RED(A1.w)
    RED(A2.x) RED(A2.y) RED(A2.z) RED(A2.w)
    RED(A3.x) RED(A3.y) RED(A3.z) RED(A3.w)
    #undef RED

    if (lane == 0) {
        float inv = 1.f / l;
        float4* yp = reinterpret_cast<float4*>(y + ((size_t)bh * T + t) * E);
        yp[0] = make_float4(A0.x * inv, A0.y * inv, A0.z * inv, A0.w * inv);
        yp[1] = make_float4(A1.x * inv, A1.y * inv, A1.z * inv, A1.w * inv);
        yp[2] = make_float4(A2.x * inv, A2.y * inv, A2.z * inv, A2.w * inv);
        yp[3] = make_float4(A3.x * inv, A3.y * inv, A3.z * inv, A3.w * inv);
    }
}

// ---------------- Kernel 3: head merge + output projection + residual ----------------
__global__ __launch_bounds__(C) void k_out(
    const float* __restrict__ y, const float* __restrict__ Wp,
    const float* __restrict__ x, float* __restrict__ out)
{
    const int row = blockIdx.x;   // b*T + t
    const int c   = threadIdx.x;
    const int b = row >> 10, t = row & (T - 1);
    __shared__ float ys[C];
    const int h = c >> 4, e = c & (E - 1);
    ys[c] = y[(((size_t)(b * H + h)) * T + t) * E + e];
    __syncthreads();
    float acc = 0.f;
    #pragma unroll 8
    for (int i = 0; i < C; ++i)
        acc = fmaf(ys[i], Wp[i * C + c], acc);
    acc += x[(size_t)row * C + c];
    out[(size_t)row * C + c] = acc;
}

extern "C" void kernel_launch(void* const* d_in, const int* in_sizes, int n_in,
                              void* d_out, int out_size, void* d_ws, size_t ws_size,
                              hipStream_t stream) {
    const float* x   = (const float*)d_in[0];
    const float* Wq  = (const float*)d_in[1];
    const float* Wk  = (const float*)d_in[2];
    const float* Wv  = (const float*)d_in[3];
    const float* Wp  = (const float*)d_in[4];
    const float* wpe = (const float*)d_in[5];
    const float* g   = (const float*)d_in[6];
    const float* bb  = (const float*)d_in[7];
    float* out = (float*)d_out;

    const size_t NQ = (size_t)B * H * T * E;   // 1,048,576 floats = 4 MB
    float* q = (float*)d_ws;
    float* k = q + NQ;
    float* v = k + NQ;
    float* y = v + NQ;                         // total 16 MB of d_ws

    k_ln_qkv<<<B * T, C, 0, stream>>>(x, Wq, Wk, Wv, g, bb, q, k, v);
    k_attn<<<(B * H * T) / 4, 256, 0, stream>>>(q, k, v, wpe, y);
    k_out<<<B * T, C, 0, stream>>>(y, Wp, x, out);
}

// Round 3
// 124.555 us; speedup vs baseline: 5.6020x; 5.6020x over previous
//
#include <hip/hip_runtime.h>
#include <hip/hip_bf16.h>

#define B 8
#define T 1024
#define C 128
#define H 8
#define E 16
#define BH (B*H)

typedef __attribute__((ext_vector_type(8)))  short bf16x8;
typedef __attribute__((ext_vector_type(16))) float f32x16;

#define QSCALE 0.36067376022224085f   // 0.25 * log2(e): folds score scale + exp2 domain

__device__ __forceinline__ unsigned short bfbits(float x) {
    __hip_bfloat16 h = __float2bfloat16(x);
    return __builtin_bit_cast(unsigned short, h);
}

// ---------------- Kernel 0: wpe -> per-head bf16 [H][1025][16] ----------------
__global__ __launch_bounds__(C) void k_wpe(const float* __restrict__ wpe,
                                           __hip_bfloat16* __restrict__ wpb) {
    int d = blockIdx.x, c = threadIdx.x;          // d in [0,1025), c in [0,128)
    int h = c >> 4, e = c & 15;
    wpb[((size_t)h * 1025 + d) * 16 + e] = __float2bfloat16(wpe[(size_t)d * C + c]);
}

// ---------------- Kernel 1: LayerNorm + QKV projection -> bf16 ----------------
// Q scaled by QSCALE; V stored transposed VT[bh][e][t]
__global__ __launch_bounds__(C) void k_ln_qkv(
    const float* __restrict__ x,
    const float* __restrict__ Wq, const float* __restrict__ Wk,
    const float* __restrict__ Wv,
    const float* __restrict__ g,  const float* __restrict__ bb,
    __hip_bfloat16* __restrict__ qb, __hip_bfloat16* __restrict__ kb,
    __hip_bfloat16* __restrict__ vt)
{
    const int row = blockIdx.x;       // b*T + t
    const int c = threadIdx.x;        // 0..127
    __shared__ float s1[C], s2[C], ln[C];
    float xv = x[(size_t)row * C + c];
    s1[c] = xv; s2[c] = xv * xv;
    __syncthreads();
    for (int st = C / 2; st > 0; st >>= 1) {
        if (c < st) { s1[c] += s1[c + st]; s2[c] += s2[c + st]; }
        __syncthreads();
    }
    float mu  = s1[0] * (1.f / C);
    float var = s2[0] * (1.f / C) - mu * mu;
    float lnv = (xv - mu) * rsqrtf(var + 1e-5f) * g[c] + bb[c];
    ln[c] = lnv;
    __syncthreads();

    float aq = 0.f, ak = 0.f, av = 0.f;
    #pragma unroll 8
    for (int i = 0; i < C; ++i) {
        float lv = ln[i];
        aq = fmaf(lv, Wq[i * C + c], aq);
        ak = fmaf(lv, Wk[i * C + c], ak);
        av = fmaf(lv, Wv[i * C + c], av);
    }
    const int b = row >> 10, t = row & (T - 1);
    const int h = c >> 4,   e = c & (E - 1);
    const int bh = b * H + h;
    size_t idx = ((size_t)bh * T + t) * E + e;    // [BH][T][E]
    qb[idx] = __float2bfloat16(aq * QSCALE);
    kb[idx] = __float2bfloat16(ak);
    vt[((size_t)bh * E + e) * T + t] = __float2bfloat16(av);   // [BH][E][T]
}

// ---------------- Kernel 2: MFMA flash attention with rel-pos ----------------
// block = 4 waves: (pair, parity). pair selects Q-block jt or 31-jt; parity splits s-tiles.
// Per wave: S^T = mfma(K,Q), U^T = mfma(WPE,Q) -> LDS diag-gather, online softmax
// (lane-local rows), P -> LDS -> PV mfma with A=V^T.
__global__ __launch_bounds__(256) void k_attn(
    const __hip_bfloat16* __restrict__ Qb, const __hip_bfloat16* __restrict__ Kb,
    const __hip_bfloat16* __restrict__ VT, const __hip_bfloat16* __restrict__ Wpb,
    float* __restrict__ y)
{
    __shared__ __align__(16) float  U_all[4][32 * 68];   // per-wave U band [t=32][d=64+pad4]
    __shared__ __align__(16) ushort P_all[4][32 * 40];   // per-wave P^T [t=32][s=32 pad40]
    __shared__ __align__(16) float  Obuf[2][32][16];     // parity-1 partial O
    __shared__ float  mlbuf[2][2][32];                   // partial m, l

    const int tid  = threadIdx.x;
    const int wv   = tid >> 6, lane = tid & 63;
    const int h5   = lane >> 5, c = lane & 31;
    const int pair = wv >> 1, parity = wv & 1;
    const int bh   = blockIdx.x >> 4, jt = blockIdx.x & 15;
    const int jq   = pair ? (31 - jt) : jt;
    const int t0   = jq << 5;
    const int hh   = bh & (H - 1);

    float*  Uw = U_all[wv];
    ushort* Pw = P_all[wv];

    // Q fragment (B-operand): lane holds Q[t0 + c][8*h5 + j]
    const bf16x8 qf = *reinterpret_cast<const bf16x8*>(
        Qb + ((size_t)(bh * T + t0 + c) * E + 8 * h5));

    f32x16 Z;
    #pragma unroll
    for (int r = 0; r < 16; ++r) Z[r] = 0.f;
    f32x16 O = Z;
    float m = -1e30f, l = 0.f;

    for (int s0 = parity * 32; s0 <= t0; s0 += 64) {
        // --- fragments (all coalesced 16B/lane) ---
        const bf16x8 kf = *reinterpret_cast<const bf16x8*>(
            Kb + ((size_t)(bh * T + s0 + c) * E + 8 * h5));
        int dhi = t0 - s0 + c;                 // in [0,1023] always
        int dlo = dhi - 32; if (dlo < 0) dlo = 0;   // clamped rows feed masked elems only
        const bf16x8 wfh = *reinterpret_cast<const bf16x8*>(
            Wpb + ((size_t)(hh * 1025 + dhi) * E + 8 * h5));
        const bf16x8 wfl = *reinterpret_cast<const bf16x8*>(
            Wpb + ((size_t)(hh * 1025 + dlo) * E + 8 * h5));

        // --- MFMAs: S^T[s,t], U^T[d,t] (cols = t = c for all) ---
        f32x16 S   = __builtin_amdgcn_mfma_f32_32x32x16_bf16(kf,  qf, Z, 0, 0, 0);
        f32x16 Ulo = __builtin_amdgcn_mfma_f32_32x32x16_bf16(wfl, qf, Z, 0, 0, 0);
        f32x16 Uhi = __builtin_amdgcn_mfma_f32_32x32x16_bf16(wfh, qf, Z, 0, 0, 0);

        // --- write U band to LDS: U_lds[t=c][slot*32 + drow], b128 quads ---
        {
            int ub = c * 68 + 4 * h5;
            *reinterpret_cast<float4*>(&Uw[ub +  0]) = make_float4(Ulo[0],  Ulo[1],  Ulo[2],  Ulo[3]);
            *reinterpret_cast<float4*>(&Uw[ub +  8]) = make_float4(Ulo[4],  Ulo[5],  Ulo[6],  Ulo[7]);
            *reinterpret_cast<float4*>(&Uw[ub + 16]) = make_float4(Ulo[8],  Ulo[9],  Ulo[10], Ulo[11]);
            *reinterpret_cast<float4*>(&Uw[ub + 24]) = make_float4(Ulo[12], Ulo[13], Ulo[14], Ulo[15]);
            *reinterpret_cast<float4*>(&Uw[ub + 32]) = make_float4(Uhi[0],  Uhi[1],  Uhi[2],  Uhi[3]);
            *reinterpret_cast<float4*>(&Uw[ub + 40]) = make_float4(Uhi[4],  Uhi[5],  Uhi[6],  Uhi[7]);
            *reinterpret_cast<float4*>(&Uw[ub + 48]) = make_float4(Uhi[8],  Uhi[9],  Uhi[10], Uhi[11]);
            *reinterpret_cast<float4*>(&Uw[ub + 56]) = make_float4(Uhi[12], Uhi[13], Uhi[14], Uhi[15]);
        }

        // --- diagonal gather + mask + online softmax (rows lane-local) ---
        // band offset for reg r: d' = c + 32 - rowmap(r), rowmap = 4*h5 + (r&3) + 8*(r>>2)
        const int ubase = c * 68 + (c - 4 * h5 + 5);
        float sc[16];
        float pmax = -1e30f;
        #pragma unroll
        for (int r = 0; r < 16; ++r) {
            float u = Uw[ubase + 27 - 8 * (r >> 2) - (r & 3)];
            int rowm = 4 * h5 + (r & 3) + 8 * (r >> 2);
            float v = S[r] + u;
            sc[r] = (s0 + rowm <= t0 + c) ? v : -1e30f;
            pmax = fmaxf(pmax, sc[r]);
        }
        float pm2 = fmaxf(pmax, __shfl_xor(pmax, 32, 64));
        float mn  = fmaxf(m, pm2);
        float f   = exp2f(m - mn);
        float ps  = 0.f;
        ushort pu[16];
        #pragma unroll
        for (int r = 0; r < 16; ++r) {
            float p = exp2f(sc[r] - mn);
            ps += p;
            pu[r] = bfbits(p);
        }
        ps += __shfl_xor(ps, 32, 64);
        l = l * f + ps;
        m = mn;
        #pragma unroll
        for (int r = 0; r < 8; ++r) O[r] *= f;   // rescale valid e-rows

        // --- P^T -> LDS: Pw[t=c][s], b64 quads ---
        {
            int pb = c * 40 + 4 * h5;
            #pragma unroll
            for (int q2 = 0; q2 < 4; ++q2) {
                uint2 w;
                w.x = (unsigned)pu[4 * q2]     | ((unsigned)pu[4 * q2 + 1] << 16);
                w.y = (unsigned)pu[4 * q2 + 2] | ((unsigned)pu[4 * q2 + 3] << 16);
                *reinterpret_cast<uint2*>(&Pw[pb + 8 * q2]) = w;
            }
        }

        // --- PV: out^T[e,t] += V^T chunk (A) x P^T chunk (B) ---
        const bf16x8 va = *reinterpret_cast<const bf16x8*>(
            VT + ((size_t)(bh * E + c) * T + s0 + 8 * h5));
        const bf16x8 vb = *reinterpret_cast<const bf16x8*>(
            VT + ((size_t)(bh * E + c) * T + s0 + 16 + 8 * h5));
        const bf16x8 pa = *reinterpret_cast<const bf16x8*>(&Pw[c * 40 + 8 * h5]);
        const bf16x8 pc = *reinterpret_cast<const bf16x8*>(&Pw[c * 40 + 16 + 8 * h5]);
        O = __builtin_amdgcn_mfma_f32_32x32x16_bf16(va, pa, O, 0, 0, 0);
        O = __builtin_amdgcn_mfma_f32_32x32x16_bf16(vb, pc, O, 0, 0, 0);
    }

    // --- merge the two s-parity partials, normalize, write y ---
    if (parity == 1) {
        *reinterpret_cast<float4*>(&Obuf[pair][c][4 * h5])     = make_float4(O[0], O[1], O[2], O[3]);
        *reinterpret_cast<float4*>(&Obuf[pair][c][4 * h5 + 8]) = make_float4(O[4], O[5], O[6], O[7]);
        if (h5 == 0) { mlbuf[pair][0][c] = m; mlbuf[pair][1][c] = l; }
    }
    __syncthreads();
    if (parity == 0) {
        float m1 = mlbuf[pair][0][c], l1 = mlbuf[pair][1][c];
        float4 o1a = *reinterpret_cast<float4*>(&Obuf[pair][c][4 * h5]);
        float4 o1b = *reinterpret_cast<float4*>(&Obuf[pair][c][4 * h5 + 8]);
        float mn = fmaxf(m, m1);
        float f0 = exp2f(m - mn), f1 = exp2f(m1 - mn);
        float inv = 1.f / (l * f0 + l1 * f1);
        float4 ya, yb2;
        ya.x  = (O[0] * f0 + o1a.x * f1) * inv;
        ya.y  = (O[1] * f0 + o1a.y * f1) * inv;
        ya.z  = (O[2] * f0 + o1a.z * f1) * inv;
        ya.w  = (O[3] * f0 + o1a.w * f1) * inv;
        yb2.x = (O[4] * f0 + o1b.x * f1) * inv;
        yb2.y = (O[5] * f0 + o1b.y * f1) * inv;
        yb2.z = (O[6] * f0 + o1b.z * f1) * inv;
        yb2.w = (O[7] * f0 + o1b.w * f1) * inv;
        float* yp = y + ((size_t)(bh * T + t0 + c) * E + 4 * h5);
        *reinterpret_cast<float4*>(yp)     = ya;
        *reinterpret_cast<float4*>(yp + 8) = yb2;
    }
}

// ---------------- Kernel 3: head merge + output projection + residual ----------------
__global__ __launch_bounds__(C) void k_out(
    const float* __restrict__ y, const float* __restrict__ Wp,
    const float* __restrict__ x, float* __restrict__ out)
{
    const int row = blockIdx.x;   // b*T + t
    const int c   = threadIdx.x;
    const int b = row >> 10, t = row & (T - 1);
    __shared__ float ys[C];
    const int h = c >> 4, e = c & (E - 1);
    ys[c] = y[(((size_t)(b * H + h)) * T + t) * E + e];
    __syncthreads();
    float acc = 0.f;
    #pragma unroll 8
    for (int i = 0; i < C; ++i)
        acc = fmaf(ys[i], Wp[i * C + c], acc);
    acc += x[(size_t)row * C + c];
    out[(size_t)row * C + c] = acc;
}

extern "C" void kernel_launch(void* const* d_in, const int* in_sizes, int n_in,
                              void* d_out, int out_size, void* d_ws, size_t ws_size,
                              hipStream_t stream) {
    const float* x   = (const float*)d_in[0];
    const float* Wq  = (const float*)d_in[1];
    const float* Wk  = (const float*)d_in[2];
    const float* Wv  = (const float*)d_in[3];
    const float* Wp  = (const float*)d_in[4];
    const float* wpe = (const float*)d_in[5];
    const float* g   = (const float*)d_in[6];
    const float* bb  = (const float*)d_in[7];
    float* out = (float*)d_out;

    // workspace layout (bf16 counts):
    //   Qb  [BH*T*E]        = 1,048,576
    //   Kb  [BH*T*E]        = 1,048,576
    //   VT  [(BH*E + 16)*T] = 1,064,960  (16-row slack for e>=16 reads)
    //   Wpb [H*1025*E]      =   131,200
    //   y   fp32 [BH*T*E]   = 1,048,576 floats
    __hip_bfloat16* Qb  = (__hip_bfloat16*)d_ws;
    __hip_bfloat16* Kb  = Qb + (size_t)BH * T * E;
    __hip_bfloat16* VT  = Kb + (size_t)BH * T * E;
    __hip_bfloat16* Wpb = VT + ((size_t)BH * E + 16) * T;
    float*          y   = (float*)(Wpb + (size_t)H * 1025 * E);

    k_wpe    <<<1025,   C,   0, stream>>>(wpe, Wpb);
    k_ln_qkv <<<B * T,  C,   0, stream>>>(x, Wq, Wk, Wv, g, bb, Qb, Kb, VT);
    k_attn   <<<BH * 16, 256, 0, stream>>>(Qb, Kb, VT, Wpb, y);
    k_out    <<<B * T,  C,   0, stream>>>(y, Wp, x, out);
}

// Round 4
// 66.640 us; speedup vs baseline: 10.4704x; 1.8691x over previous
//
#include <hip/hip_runtime.h>
#include <hip/hip_bf16.h>

#define B 8
#define T 1024
#define C 128
#define H 8
#define E 16
#define BH (B*H)

typedef __attribute__((ext_vector_type(4)))  short bf16x4;
typedef __attribute__((ext_vector_type(8)))  short bf16x8;
typedef __attribute__((ext_vector_type(16))) float f32x16;

#define QSCALE 0.36067376022224085f   // 0.25 * log2(e): folds score scale + exp2 domain

__device__ __forceinline__ unsigned short bfbits(float x) {
    __hip_bfloat16 h = __float2bfloat16(x);
    return __builtin_bit_cast(unsigned short, h);
}
__device__ __forceinline__ unsigned pack2(float a, float b) {
    return (unsigned)bfbits(a) | ((unsigned)bfbits(b) << 16);
}

// ---------------- Kernel 0: prep — wpe per-head repack + weight transposes ----------------
// grid 1025 + 512 blocks of 128 threads
__global__ __launch_bounds__(C) void k_prep(
    const float* __restrict__ wpe,
    const float* __restrict__ Wq, const float* __restrict__ Wk,
    const float* __restrict__ Wv, const float* __restrict__ Wp,
    __hip_bfloat16* __restrict__ Wpb,   // [H][1025][16]
    __hip_bfloat16* __restrict__ WT,    // [384][128]  rows: 0-127 Q(scaled), 128-255 K, 256-383 V
    __hip_bfloat16* __restrict__ WpT)   // [128][128]
{
    int bid = blockIdx.x, tid = threadIdx.x;
    if (bid < 1025) {
        int h = tid >> 4, e = tid & 15;
        Wpb[((size_t)h * 1025 + bid) * 16 + e] = __float2bfloat16(wpe[(size_t)bid * C + tid]);
    } else {
        int n = bid - 1025;   // 0..511
        if (n < 128)      WT[n * C + tid]          = __float2bfloat16(Wq[tid * C + n] * QSCALE);
        else if (n < 256) WT[n * C + tid]          = __float2bfloat16(Wk[tid * C + (n - 128)]);
        else if (n < 384) WT[n * C + tid]          = __float2bfloat16(Wv[tid * C + (n - 256)]);
        else              WpT[(n - 384) * C + tid] = __float2bfloat16(Wp[tid * C + (n - 384)]);
    }
}

// ---------------- Kernel 1: LayerNorm + QKV projection via MFMA ----------------
// block = 256 threads = 4 waves; M-tile = 32 rows; grid 256
__global__ __launch_bounds__(256) void k_qkv(
    const float* __restrict__ x, const float* __restrict__ g, const float* __restrict__ bb,
    const __hip_bfloat16* __restrict__ WT,
    __hip_bfloat16* __restrict__ Qb, __hip_bfloat16* __restrict__ Kb,
    __hip_bfloat16* __restrict__ VT)
{
    __shared__ ushort lnlds[32 * 132];   // ln tile bf16 [32][128 + 4 pad]
    const int tid = threadIdx.x;

    // ---- LN phase: 8 threads per row, 16 cols each ----
    {
        const int r = tid >> 3, qq = tid & 7;
        const float* xp = x + ((size_t)blockIdx.x * 32 + r) * C + qq * 16;
        float4 x0 = ((const float4*)xp)[0];
        float4 x1 = ((const float4*)xp)[1];
        float4 x2 = ((const float4*)xp)[2];
        float4 x3 = ((const float4*)xp)[3];
        float s1v = x0.x + x0.y + x0.z + x0.w + x1.x + x1.y + x1.z + x1.w
                  + x2.x + x2.y + x2.z + x2.w + x3.x + x3.y + x3.z + x3.w;
        float s2v = x0.x*x0.x + x0.y*x0.y + x0.z*x0.z + x0.w*x0.w
                  + x1.x*x1.x + x1.y*x1.y + x1.z*x1.z + x1.w*x1.w
                  + x2.x*x2.x + x2.y*x2.y + x2.z*x2.z + x2.w*x2.w
                  + x3.x*x3.x + x3.y*x3.y + x3.z*x3.z + x3.w*x3.w;
        s1v += __shfl_xor(s1v, 1, 64); s2v += __shfl_xor(s2v, 1, 64);
        s1v += __shfl_xor(s1v, 2, 64); s2v += __shfl_xor(s2v, 2, 64);
        s1v += __shfl_xor(s1v, 4, 64); s2v += __shfl_xor(s2v, 4, 64);
        float mu  = s1v * (1.f / C);
        float var = s2v * (1.f / C) - mu * mu;
        float rs  = rsqrtf(var + 1e-5f);
        const float4* gp = (const float4*)(g  + qq * 16);
        const float4* bp = (const float4*)(bb + qq * 16);
        float4 g0 = gp[0], g1 = gp[1], g2 = gp[2], g3 = gp[3];
        float4 b0 = bp[0], b1 = bp[1], b2 = bp[2], b3 = bp[3];
        #define LNV(xx, gg, bv) (((xx) - mu) * rs * (gg) + (bv))
        uint2* dst = (uint2*)&lnlds[r * 132 + qq * 16];
        dst[0] = make_uint2(pack2(LNV(x0.x,g0.x,b0.x), LNV(x0.y,g0.y,b0.y)),
                            pack2(LNV(x0.z,g0.z,b0.z), LNV(x0.w,g0.w,b0.w)));
        dst[1] = make_uint2(pack2(LNV(x1.x,g1.x,b1.x), LNV(x1.y,g1.y,b1.y)),
                            pack2(LNV(x1.z,g1.z,b1.z), LNV(x1.w,g1.w,b1.w)));
        dst[2] = make_uint2(pack2(LNV(x2.x,g2.x,b2.x), LNV(x2.y,g2.y,b2.y)),
                            pack2(LNV(x2.z,g2.z,b2.z), LNV(x2.w,g2.w,b2.w)));
        dst[3] = make_uint2(pack2(LNV(x3.x,g3.x,b3.x), LNV(x3.y,g3.y,b3.y)),
                            pack2(LNV(x3.z,g3.z,b3.z), LNV(x3.w,g3.w,b3.w)));
        #undef LNV
    }
    __syncthreads();

    // ---- GEMM phase: wave wv handles N-tiles 3wv..3wv+2 of 12 (Q:0-3, K:4-7, V:8-11) ----
    const int wv = tid >> 6, lane = tid & 63, c = lane & 31, h5 = lane >> 5;
    const int b = blockIdx.x >> 5, trow = (blockIdx.x & 31) * 32;
    f32x16 Z;
    #pragma unroll
    for (int r = 0; r < 16; ++r) Z[r] = 0.f;

    for (int it = 0; it < 3; ++it) {
        const int nt = wv * 3 + it, n0 = nt * 32;
        bf16x8 wf[8], lf[8];
        #pragma unroll
        for (int s = 0; s < 8; ++s)
            wf[s] = *(const bf16x8*)(WT + (size_t)(n0 + c) * C + 16 * s + 8 * h5);
        #pragma unroll
        for (int s = 0; s < 8; ++s) {
            const ushort* lp = &lnlds[c * 132 + 16 * s + 8 * h5];
            bf16x4 lo = *(const bf16x4*)lp;
            bf16x4 hi = *(const bf16x4*)(lp + 4);
            lf[s] = __builtin_shufflevector(lo, hi, 0, 1, 2, 3, 4, 5, 6, 7);
        }
        f32x16 acc = Z;
        if (nt < 8) {
            // D[n-reg][t-lane] = WT-rows x ln-rows
            #pragma unroll
            for (int s = 0; s < 8; ++s)
                acc = __builtin_amdgcn_mfma_f32_32x32x16_bf16(wf[s], lf[s], acc, 0, 0, 0);
            __hip_bfloat16* base = (nt < 4) ? Qb : Kb;
            const int nb = (nt < 4 ? n0 : n0 - 128) + 4 * h5;
            #pragma unroll
            for (int j2 = 0; j2 < 4; ++j2) {
                int n = nb + 8 * j2;               // col in [0,128)
                int h = n >> 4, e = n & 15;
                uint2 w = make_uint2(pack2(acc[4*j2], acc[4*j2+1]),
                                     pack2(acc[4*j2+2], acc[4*j2+3]));
                *(uint2*)(base + ((size_t)(b * H + h) * T + trow + c) * E + e) = w;
            }
        } else {
            // D[t-reg][e-lane] = ln-rows x WT-rows  -> writes VT transposed directly
            #pragma unroll
            for (int s = 0; s < 8; ++s)
                acc = __builtin_amdgcn_mfma_f32_32x32x16_bf16(lf[s], wf[s], acc, 0, 0, 0);
            const int ecol = n0 - 256 + c;          // 0..127
            const int h = ecol >> 4, e = ecol & 15;
            __hip_bfloat16* vbase = VT + ((size_t)(b * H + h) * E + e) * T + trow + 4 * h5;
            #pragma unroll
            for (int j2 = 0; j2 < 4; ++j2) {
                uint2 w = make_uint2(pack2(acc[4*j2], acc[4*j2+1]),
                                     pack2(acc[4*j2+2], acc[4*j2+3]));
                *(uint2*)(vbase + 8 * j2) = w;
            }
        }
    }
}

// ---------------- Kernel 2: MFMA flash attention with rel-pos ----------------
__global__ __launch_bounds__(256) void k_attn(
    const __hip_bfloat16* __restrict__ Qb, const __hip_bfloat16* __restrict__ Kb,
    const __hip_bfloat16* __restrict__ VT, const __hip_bfloat16* __restrict__ Wpb,
    __hip_bfloat16* __restrict__ yb)
{
    __shared__ __align__(16) float  U_all[4][32 * 68];
    __shared__ __align__(16) ushort P_all[4][32 * 40];
    __shared__ __align__(16) float  Obuf[2][32][16];
    __shared__ float  mlbuf[2][2][32];

    const int tid  = threadIdx.x;
    const int wv   = tid >> 6, lane = tid & 63;
    const int h5   = lane >> 5, c = lane & 31;
    const int pair = wv >> 1, parity = wv & 1;
    const int bh   = blockIdx.x >> 4, jt = blockIdx.x & 15;
    const int jq   = pair ? (31 - jt) : jt;
    const int t0   = jq << 5;
    const int hh   = bh & (H - 1);

    float*  Uw = U_all[wv];
    ushort* Pw = P_all[wv];

    const bf16x8 qf = *reinterpret_cast<const bf16x8*>(
        Qb + ((size_t)(bh * T + t0 + c) * E + 8 * h5));

    f32x16 Z;
    #pragma unroll
    for (int r = 0; r < 16; ++r) Z[r] = 0.f;
    f32x16 O = Z;
    float m = -1e30f, l = 0.f;

    for (int s0 = parity * 32; s0 <= t0; s0 += 64) {
        const bf16x8 kf = *reinterpret_cast<const bf16x8*>(
            Kb + ((size_t)(bh * T + s0 + c) * E + 8 * h5));
        int dhi = t0 - s0 + c;
        int dlo = dhi - 32; if (dlo < 0) dlo = 0;
        const bf16x8 wfh = *reinterpret_cast<const bf16x8*>(
            Wpb + ((size_t)(hh * 1025 + dhi) * E + 8 * h5));
        const bf16x8 wfl = *reinterpret_cast<const bf16x8*>(
            Wpb + ((size_t)(hh * 1025 + dlo) * E + 8 * h5));

        f32x16 S   = __builtin_amdgcn_mfma_f32_32x32x16_bf16(kf,  qf, Z, 0, 0, 0);
        f32x16 Ulo = __builtin_amdgcn_mfma_f32_32x32x16_bf16(wfl, qf, Z, 0, 0, 0);
        f32x16 Uhi = __builtin_amdgcn_mfma_f32_32x32x16_bf16(wfh, qf, Z, 0, 0, 0);

        {
            int ub = c * 68 + 4 * h5;
            *reinterpret_cast<float4*>(&Uw[ub +  0]) = make_float4(Ulo[0],  Ulo[1],  Ulo[2],  Ulo[3]);
            *reinterpret_cast<float4*>(&Uw[ub +  8]) = make_float4(Ulo[4],  Ulo[5],  Ulo[6],  Ulo[7]);
            *reinterpret_cast<float4*>(&Uw[ub + 16]) = make_float4(Ulo[8],  Ulo[9],  Ulo[10], Ulo[11]);
            *reinterpret_cast<float4*>(&Uw[ub + 24]) = make_float4(Ulo[12], Ulo[13], Ulo[14], Ulo[15]);
            *reinterpret_cast<float4*>(&Uw[ub + 32]) = make_float4(Uhi[0],  Uhi[1],  Uhi[2],  Uhi[3]);
            *reinterpret_cast<float4*>(&Uw[ub + 40]) = make_float4(Uhi[4],  Uhi[5],  Uhi[6],  Uhi[7]);
            *reinterpret_cast<float4*>(&Uw[ub + 48]) = make_float4(Uhi[8],  Uhi[9],  Uhi[10], Uhi[11]);
            *reinterpret_cast<float4*>(&Uw[ub + 56]) = make_float4(Uhi[12], Uhi[13], Uhi[14], Uhi[15]);
        }

        const int ubase = c * 68 + (c - 4 * h5 + 5);
        float sc[16];
        float pmax = -1e30f;
        #pragma unroll
        for (int r = 0; r < 16; ++r) {
            float u = Uw[ubase + 27 - 8 * (r >> 2) - (r & 3)];
            int rowm = 4 * h5 + (r & 3) + 8 * (r >> 2);
            float v = S[r] + u;
            sc[r] = (s0 + rowm <= t0 + c) ? v : -1e30f;
            pmax = fmaxf(pmax, sc[r]);
        }
        float pm2 = fmaxf(pmax, __shfl_xor(pmax, 32, 64));
        float mn  = fmaxf(m, pm2);
        float f   = exp2f(m - mn);
        float ps  = 0.f;
        ushort pu[16];
        #pragma unroll
        for (int r = 0; r < 16; ++r) {
            float p = exp2f(sc[r] - mn);
            ps += p;
            pu[r] = bfbits(p);
        }
        ps += __shfl_xor(ps, 32, 64);
        l = l * f + ps;
        m = mn;
        #pragma unroll
        for (int r = 0; r < 8; ++r) O[r] *= f;

        {
            int pb = c * 40 + 4 * h5;
            #pragma unroll
            for (int q2 = 0; q2 < 4; ++q2) {
                uint2 w;
                w.x = (unsigned)pu[4 * q2]     | ((unsigned)pu[4 * q2 + 1] << 16);
                w.y = (unsigned)pu[4 * q2 + 2] | ((unsigned)pu[4 * q2 + 3] << 16);
                *reinterpret_cast<uint2*>(&Pw[pb + 8 * q2]) = w;
            }
        }

        const bf16x8 va = *reinterpret_cast<const bf16x8*>(
            VT + ((size_t)(bh * E + c) * T + s0 + 8 * h5));
        const bf16x8 vb = *reinterpret_cast<const bf16x8*>(
            VT + ((size_t)(bh * E + c) * T + s0 + 16 + 8 * h5));
        const bf16x8 pa = *reinterpret_cast<const bf16x8*>(&Pw[c * 40 + 8 * h5]);
        const bf16x8 pc = *reinterpret_cast<const bf16x8*>(&Pw[c * 40 + 16 + 8 * h5]);
        O = __builtin_amdgcn_mfma_f32_32x32x16_bf16(va, pa, O, 0, 0, 0);
        O = __builtin_amdgcn_mfma_f32_32x32x16_bf16(vb, pc, O, 0, 0, 0);
    }

    if (parity == 1) {
        *reinterpret_cast<float4*>(&Obuf[pair][c][4 * h5])     = make_float4(O[0], O[1], O[2], O[3]);
        *reinterpret_cast<float4*>(&Obuf[pair][c][4 * h5 + 8]) = make_float4(O[4], O[5], O[6], O[7]);
        if (h5 == 0) { mlbuf[pair][0][c] = m; mlbuf[pair][1][c] = l; }
    }
    __syncthreads();
    if (parity == 0) {
        float m1 = mlbuf[pair][0][c], l1 = mlbuf[pair][1][c];
        float4 o1a = *reinterpret_cast<float4*>(&Obuf[pair][c][4 * h5]);
        float4 o1b = *reinterpret_cast<float4*>(&Obuf[pair][c][4 * h5 + 8]);
        float mn = fmaxf(m, m1);
        float f0 = exp2f(m - mn), f1 = exp2f(m1 - mn);
        float inv = 1.f / (l * f0 + l1 * f1);
        float4 ya, yb2;
        ya.x  = (O[0] * f0 + o1a.x * f1) * inv;
        ya.y  = (O[1] * f0 + o1a.y * f1) * inv;
        ya.z  = (O[2] * f0 + o1a.z * f1) * inv;
        ya.w  = (O[3] * f0 + o1a.w * f1) * inv;
        yb2.x = (O[4] * f0 + o1b.x * f1) * inv;
        yb2.y = (O[5] * f0 + o1b.y * f1) * inv;
        yb2.z = (O[6] * f0 + o1b.z * f1) * inv;
        yb2.w = (O[7] * f0 + o1b.w * f1) * inv;
        // y as bf16, head-merged layout [b][t][C]
        __hip_bfloat16* yp = yb + ((size_t)((bh >> 3) * T + t0 + c)) * C + (bh & 7) * E + 4 * h5;
        *reinterpret_cast<uint2*>(yp)     = make_uint2(pack2(ya.x,  ya.y),  pack2(ya.z,  ya.w));
        *reinterpret_cast<uint2*>(yp + 8) = make_uint2(pack2(yb2.x, yb2.y), pack2(yb2.z, yb2.w));
    }
}

// ---------------- Kernel 3: output projection + residual via MFMA ----------------
// block = 256 threads = 4 waves; M-tile = 32 rows; wave wv = N-tile wv; grid 256
__global__ __launch_bounds__(256) void k_proj(
    const __hip_bfloat16* __restrict__ yb, const __hip_bfloat16* __restrict__ WpT,
    const float* __restrict__ x, float* __restrict__ out)
{
    __shared__ ushort ylds[32 * 132];
    const int tid = threadIdx.x;
    const size_t row0 = (size_t)blockIdx.x * 32;

    #pragma unroll
    for (int ch = 0; ch < 2; ++ch) {
        int idx = tid + ch * 256;
        int r = idx >> 4, c8 = (idx & 15) * 8;
        const ushort* src = (const ushort*)yb + (row0 + r) * C + c8;
        uint4 a = *(const uint4*)src;
        *(uint2*)&ylds[r * 132 + c8]     = make_uint2(a.x, a.y);
        *(uint2*)&ylds[r * 132 + c8 + 4] = make_uint2(a.z, a.w);
    }
    __syncthreads();

    const int wv = tid >> 6, lane = tid & 63, c = lane & 31, h5 = lane >> 5;
    const int n0 = wv * 32;
    bf16x8 wf[8], yf[8];
    #pragma unroll
    for (int s = 0; s < 8; ++s)
        wf[s] = *(const bf16x8*)(WpT + (size_t)(n0 + c) * C + 16 * s + 8 * h5);
    #pragma unroll
    for (int s = 0; s < 8; ++s) {
        const ushort* lp = &ylds[c * 132 + 16 * s + 8 * h5];
        bf16x4 lo = *(const bf16x4*)lp;
        bf16x4 hi = *(const bf16x4*)(lp + 4);
        yf[s] = __builtin_shufflevector(lo, hi, 0, 1, 2, 3, 4, 5, 6, 7);
    }
    f32x16 acc;
    #pragma unroll
    for (int r = 0; r < 16; ++r) acc[r] = 0.f;
    #pragma unroll
    for (int s = 0; s < 8; ++s)
        acc = __builtin_amdgcn_mfma_f32_32x32x16_bf16(wf[s], yf[s], acc, 0, 0, 0);

    // D[n-reg][t-lane]; out fp32 [row][128] + residual x
    const size_t rb = (row0 + c) * C;
    #pragma unroll
    for (int j2 = 0; j2 < 4; ++j2) {
        int n = n0 + 4 * h5 + 8 * j2;
        float4 xr = *(const float4*)(x + rb + n);
        float4 o  = make_float4(acc[4*j2] + xr.x, acc[4*j2+1] + xr.y,
                                acc[4*j2+2] + xr.z, acc[4*j2+3] + xr.w);
        *(float4*)(out + rb + n) = o;
    }
}

extern "C" void kernel_launch(void* const* d_in, const int* in_sizes, int n_in,
                              void* d_out, int out_size, void* d_ws, size_t ws_size,
                              hipStream_t stream) {
    const float* x   = (const float*)d_in[0];
    const float* Wq  = (const float*)d_in[1];
    const float* Wk  = (const float*)d_in[2];
    const float* Wv  = (const float*)d_in[3];
    const float* Wp  = (const float*)d_in[4];
    const float* wpe = (const float*)d_in[5];
    const float* g   = (const float*)d_in[6];
    const float* bb  = (const float*)d_in[7];
    float* out = (float*)d_out;

    // workspace (ushort units)
    ushort* w = (ushort*)d_ws;
    __hip_bfloat16* Qb  = (__hip_bfloat16*)(w);                 // 1,048,576
    __hip_bfloat16* Kb  = (__hip_bfloat16*)(w + 1048576);       // 1,048,576
    __hip_bfloat16* VT  = (__hip_bfloat16*)(w + 2097152);       // 1,064,960 (+16 slack rows)
    __hip_bfloat16* Wpb = (__hip_bfloat16*)(w + 3162112);       //   131,200
    __hip_bfloat16* WT  = (__hip_bfloat16*)(w + 3293312);       //    49,152
    __hip_bfloat16* WpT = (__hip_bfloat16*)(w + 3342464);       //    16,384
    __hip_bfloat16* yb  = (__hip_bfloat16*)(w + 3358848);       // 1,048,576

    k_prep <<<1025 + 512, C,   0, stream>>>(wpe, Wq, Wk, Wv, Wp, Wpb, WT, WpT);
    k_qkv  <<<256,        256, 0, stream>>>(x, g, bb, WT, Qb, Kb, VT);
    k_attn <<<BH * 16,    256, 0, stream>>>(Qb, Kb, VT, Wpb, yb);
    k_proj <<<256,        256, 0, stream>>>(yb, WpT, x, out);
}

// Round 5
// 57.103 us; speedup vs baseline: 12.2191x; 1.1670x over previous
//
#include <hip/hip_runtime.h>
#include <hip/hip_bf16.h>

#define B 8
#define T 1024
#define C 128
#define H 8
#define E 16
#define BH (B*H)

typedef __attribute__((ext_vector_type(4)))  short bf16x4;
typedef __attribute__((ext_vector_type(8)))  short bf16x8;
typedef __attribute__((ext_vector_type(16))) float f32x16;

#define QSCALE 0.36067376022224085f   // 0.25 * log2(e): folds score scale + exp2 domain

__device__ __forceinline__ unsigned short bfbits(float x) {
    __hip_bfloat16 h = __float2bfloat16(x);
    return __builtin_bit_cast(unsigned short, h);
}
__device__ __forceinline__ unsigned pack2(float a, float b) {
    return (unsigned)bfbits(a) | ((unsigned)bfbits(b) << 16);
}

// ---------------- Kernel 0: prep — wpe per-head repack + weight transposes ----------------
__global__ __launch_bounds__(C) void k_prep(
    const float* __restrict__ wpe,
    const float* __restrict__ Wq, const float* __restrict__ Wk,
    const float* __restrict__ Wv, const float* __restrict__ Wp,
    __hip_bfloat16* __restrict__ Wpb,   // [H][1025][16]
    __hip_bfloat16* __restrict__ WT,    // [384][128]  rows: 0-127 Q(scaled), 128-255 K, 256-383 V
    __hip_bfloat16* __restrict__ WpT)   // [128][128]
{
    int bid = blockIdx.x, tid = threadIdx.x;
    if (bid < 1025) {
        int h = tid >> 4, e = tid & 15;
        Wpb[((size_t)h * 1025 + bid) * 16 + e] = __float2bfloat16(wpe[(size_t)bid * C + tid]);
    } else {
        int n = bid - 1025;   // 0..511
        if (n < 128)      WT[n * C + tid]          = __float2bfloat16(Wq[tid * C + n] * QSCALE);
        else if (n < 256) WT[n * C + tid]          = __float2bfloat16(Wk[tid * C + (n - 128)]);
        else if (n < 384) WT[n * C + tid]          = __float2bfloat16(Wv[tid * C + (n - 256)]);
        else              WpT[(n - 384) * C + tid] = __float2bfloat16(Wp[tid * C + (n - 384)]);
    }
}

// ---------------- Kernel 1: LayerNorm + QKV projection via MFMA ----------------
__global__ __launch_bounds__(256) void k_qkv(
    const float* __restrict__ x, const float* __restrict__ g, const float* __restrict__ bb,
    const __hip_bfloat16* __restrict__ WT,
    __hip_bfloat16* __restrict__ Qb, __hip_bfloat16* __restrict__ Kb,
    __hip_bfloat16* __restrict__ VT)
{
    __shared__ ushort lnlds[32 * 132];
    const int tid = threadIdx.x;

    {
        const int r = tid >> 3, qq = tid & 7;
        const float* xp = x + ((size_t)blockIdx.x * 32 + r) * C + qq * 16;
        float4 x0 = ((const float4*)xp)[0];
        float4 x1 = ((const float4*)xp)[1];
        float4 x2 = ((const float4*)xp)[2];
        float4 x3 = ((const float4*)xp)[3];
        float s1v = x0.x + x0.y + x0.z + x0.w + x1.x + x1.y + x1.z + x1.w
                  + x2.x + x2.y + x2.z + x2.w + x3.x + x3.y + x3.z + x3.w;
        float s2v = x0.x*x0.x + x0.y*x0.y + x0.z*x0.z + x0.w*x0.w
                  + x1.x*x1.x + x1.y*x1.y + x1.z*x1.z + x1.w*x1.w
                  + x2.x*x2.x + x2.y*x2.y + x2.z*x2.z + x2.w*x2.w
                  + x3.x*x3.x + x3.y*x3.y + x3.z*x3.z + x3.w*x3.w;
        s1v += __shfl_xor(s1v, 1, 64); s2v += __shfl_xor(s2v, 1, 64);
        s1v += __shfl_xor(s1v, 2, 64); s2v += __shfl_xor(s2v, 2, 64);
        s1v += __shfl_xor(s1v, 4, 64); s2v += __shfl_xor(s2v, 4, 64);
        float mu  = s1v * (1.f / C);
        float var = s2v * (1.f / C) - mu * mu;
        float rs  = rsqrtf(var + 1e-5f);
        const float4* gp = (const float4*)(g  + qq * 16);
        const float4* bp = (const float4*)(bb + qq * 16);
        float4 g0 = gp[0], g1 = gp[1], g2 = gp[2], g3 = gp[3];
        float4 b0 = bp[0], b1 = bp[1], b2 = bp[2], b3 = bp[3];
        #define LNV(xx, gg, bv) (((xx) - mu) * rs * (gg) + (bv))
        uint2* dst = (uint2*)&lnlds[r * 132 + qq * 16];
        dst[0] = make_uint2(pack2(LNV(x0.x,g0.x,b0.x), LNV(x0.y,g0.y,b0.y)),
                            pack2(LNV(x0.z,g0.z,b0.z), LNV(x0.w,g0.w,b0.w)));
        dst[1] = make_uint2(pack2(LNV(x1.x,g1.x,b1.x), LNV(x1.y,g1.y,b1.y)),
                            pack2(LNV(x1.z,g1.z,b1.z), LNV(x1.w,g1.w,b1.w)));
        dst[2] = make_uint2(pack2(LNV(x2.x,g2.x,b2.x), LNV(x2.y,g2.y,b2.y)),
                            pack2(LNV(x2.z,g2.z,b2.z), LNV(x2.w,g2.w,b2.w)));
        dst[3] = make_uint2(pack2(LNV(x3.x,g3.x,b3.x), LNV(x3.y,g3.y,b3.y)),
                            pack2(LNV(x3.z,g3.z,b3.z), LNV(x3.w,g3.w,b3.w)));
        #undef LNV
    }
    __syncthreads();

    const int wv = tid >> 6, lane = tid & 63, c = lane & 31, h5 = lane >> 5;
    const int b = blockIdx.x >> 5, trow = (blockIdx.x & 31) * 32;
    f32x16 Z;
    #pragma unroll
    for (int r = 0; r < 16; ++r) Z[r] = 0.f;

    for (int it = 0; it < 3; ++it) {
        const int nt = wv * 3 + it, n0 = nt * 32;
        bf16x8 wf[8], lf[8];
        #pragma unroll
        for (int s = 0; s < 8; ++s)
            wf[s] = *(const bf16x8*)(WT + (size_t)(n0 + c) * C + 16 * s + 8 * h5);
        #pragma unroll
        for (int s = 0; s < 8; ++s) {
            const ushort* lp = &lnlds[c * 132 + 16 * s + 8 * h5];
            bf16x4 lo = *(const bf16x4*)lp;
            bf16x4 hi = *(const bf16x4*)(lp + 4);
            lf[s] = __builtin_shufflevector(lo, hi, 0, 1, 2, 3, 4, 5, 6, 7);
        }
        f32x16 acc = Z;
        if (nt < 8) {
            #pragma unroll
            for (int s = 0; s < 8; ++s)
                acc = __builtin_amdgcn_mfma_f32_32x32x16_bf16(wf[s], lf[s], acc, 0, 0, 0);
            __hip_bfloat16* base = (nt < 4) ? Qb : Kb;
            const int nb = (nt < 4 ? n0 : n0 - 128) + 4 * h5;
            #pragma unroll
            for (int j2 = 0; j2 < 4; ++j2) {
                int n = nb + 8 * j2;
                int h = n >> 4, e = n & 15;
                uint2 w = make_uint2(pack2(acc[4*j2], acc[4*j2+1]),
                                     pack2(acc[4*j2+2], acc[4*j2+3]));
                *(uint2*)(base + ((size_t)(b * H + h) * T + trow + c) * E + e) = w;
            }
        } else {
            #pragma unroll
            for (int s = 0; s < 8; ++s)
                acc = __builtin_amdgcn_mfma_f32_32x32x16_bf16(lf[s], wf[s], acc, 0, 0, 0);
            const int ecol = n0 - 256 + c;
            const int h = ecol >> 4, e = ecol & 15;
            __hip_bfloat16* vbase = VT + ((size_t)(b * H + h) * E + e) * T + trow + 4 * h5;
            #pragma unroll
            for (int j2 = 0; j2 < 4; ++j2) {
                uint2 w = make_uint2(pack2(acc[4*j2], acc[4*j2+1]),
                                     pack2(acc[4*j2+2], acc[4*j2+3]));
                *(uint2*)(vbase + 8 * j2) = w;
            }
        }
    }
}

// ---------------- Kernel 2: MFMA flash attention, balanced 2-state waves ----------------
template<bool DIAG>
__device__ __forceinline__ void attn_tile(
    const __hip_bfloat16* __restrict__ Kb, const __hip_bfloat16* __restrict__ VT,
    const __hip_bfloat16* __restrict__ Wpb,
    int bh, int hh, int c, int h5, int s0, int t0,
    const bf16x8 qf, float* __restrict__ Uw,
    f32x16& O, float& m, float& l)
{
    f32x16 Z;
    #pragma unroll
    for (int r = 0; r < 16; ++r) Z[r] = 0.f;

    const bf16x8 kf = *(const bf16x8*)(Kb + ((size_t)(bh * T + s0 + c) * E + 8 * h5));
    int dhi = t0 - s0 + c;
    int dlo = dhi - 32;
    if (DIAG) { if (dlo < 0) dlo = 0; }          // clamped rows feed masked entries only
    const bf16x8 wfh = *(const bf16x8*)(Wpb + ((size_t)(hh * 1025 + dhi) * E + 8 * h5));
    const bf16x8 wfl = *(const bf16x8*)(Wpb + ((size_t)(hh * 1025 + dlo) * E + 8 * h5));

    f32x16 S   = __builtin_amdgcn_mfma_f32_32x32x16_bf16(kf,  qf, Z, 0, 0, 0);
    f32x16 Ulo = __builtin_amdgcn_mfma_f32_32x32x16_bf16(wfl, qf, Z, 0, 0, 0);
    f32x16 Uhi = __builtin_amdgcn_mfma_f32_32x32x16_bf16(wfh, qf, Z, 0, 0, 0);

    // U band -> LDS, XOR-swizzled (conflict-free float4 phases)
    const int urow = c * 64, sw = (c & 7) << 2;
    #define UST(col4, vv, o) *(float4*)&Uw[urow + (((col4)) ^ sw)] = \
        make_float4(vv[o], vv[o+1], vv[o+2], vv[o+3])
    UST( 0 + 4*h5, Ulo, 0);  UST( 8 + 4*h5, Ulo, 4);
    UST(16 + 4*h5, Ulo, 8);  UST(24 + 4*h5, Ulo, 12);
    UST(32 + 4*h5, Uhi, 0);  UST(40 + 4*h5, Uhi, 4);
    UST(48 + 4*h5, Uhi, 8);  UST(56 + 4*h5, Uhi, 12);
    #undef UST

    // diagonal gather + mask + online softmax (rows lane-local, exp2 domain)
    float sc[16];
    float pmax = -1e30f;
    #pragma unroll
    for (int r = 0; r < 16; ++r) {
        const int rowm = 4 * h5 + (r & 3) + 8 * (r >> 2);
        float u = Uw[urow + ((c - rowm + 32) ^ sw)];
        float vv = S[r] + u;
        if (DIAG) vv = (rowm <= c) ? vv : -1e30f;
        sc[r] = vv;
        pmax = fmaxf(pmax, vv);
    }
    pmax = fmaxf(pmax, __shfl_xor(pmax, 32, 64));
    const float mn = fmaxf(m, pmax);
    const float f = exp2f(m - mn);
    float ps = 0.f;
    float p[16];
    #pragma unroll
    for (int r = 0; r < 16; ++r) { p[r] = exp2f(sc[r] - mn); ps += p[r]; }
    ps += __shfl_xor(ps, 32, 64);
    l = l * f + ps;
    m = mn;
    #pragma unroll
    for (int r = 0; r < 8; ++r) O[r] *= f;

    // P -> bf16 B-fragments in-register (pack + cross-half shfl, no LDS)
    unsigned w0 = pack2(p[0], p[1]),  w1 = pack2(p[2], p[3]);
    unsigned w2 = pack2(p[4], p[5]),  w3 = pack2(p[6], p[7]);
    unsigned w4 = pack2(p[8], p[9]),  w5 = pack2(p[10], p[11]);
    unsigned w6 = pack2(p[12], p[13]), w7 = pack2(p[14], p[15]);
    unsigned r1 = __shfl_xor(h5 ? w0 : w2, 32, 64);
    unsigned r2 = __shfl_xor(h5 ? w1 : w3, 32, 64);
    unsigned r3 = __shfl_xor(h5 ? w4 : w6, 32, 64);
    unsigned r4 = __shfl_xor(h5 ? w5 : w7, 32, 64);
    uint4 f1 = h5 ? make_uint4(r1, r2, w2, w3) : make_uint4(w0, w1, r1, r2);
    uint4 f2 = h5 ? make_uint4(r3, r4, w6, w7) : make_uint4(w4, w5, r3, r4);
    bf16x8 pb1 = __builtin_bit_cast(bf16x8, f1);
    bf16x8 pb2 = __builtin_bit_cast(bf16x8, f2);

    const bf16x8 va = *(const bf16x8*)(VT + ((size_t)(bh * E + c) * T + s0 + 8 * h5));
    const bf16x8 vb = *(const bf16x8*)(VT + ((size_t)(bh * E + c) * T + s0 + 16 + 8 * h5));
    O = __builtin_amdgcn_mfma_f32_32x32x16_bf16(va, pb1, O, 0, 0, 0);
    O = __builtin_amdgcn_mfma_f32_32x32x16_bf16(vb, pb2, O, 0, 0, 0);
}

__global__ __launch_bounds__(256) void k_attn(
    const __hip_bfloat16* __restrict__ Qb, const __hip_bfloat16* __restrict__ Kb,
    const __hip_bfloat16* __restrict__ VT, const __hip_bfloat16* __restrict__ Wpb,
    __hip_bfloat16* __restrict__ yb)
{
    __shared__ __align__(16) float U_all[4 * 32 * 64];   // 32 KB; reused for O partials
    __shared__ float mlb[2][4][2][32];                    // 2 KB

    const int tid = threadIdx.x, wv = tid >> 6, lane = tid & 63;
    const int h5 = lane >> 5, c = lane & 31;
    const int bh = blockIdx.x >> 4, jt = blockIdx.x & 15;
    const int hh = bh & (H - 1);
    const int t0A = jt << 5, t0B = (31 - jt) << 5;
    float* Uw = U_all + wv * (32 * 64);

    const bf16x8 qfA = *(const bf16x8*)(Qb + ((size_t)(bh * T + t0A + c) * E + 8 * h5));
    const bf16x8 qfB = *(const bf16x8*)(Qb + ((size_t)(bh * T + t0B + c) * E + 8 * h5));

    f32x16 OA, OB;
    #pragma unroll
    for (int r = 0; r < 16; ++r) { OA[r] = 0.f; OB[r] = 0.f; }
    float mA = -1e30f, lA = 0.f, mB = -1e30f, lB = 0.f;

    // state A: Q-tile jt (jt+1 s-tiles), strided over 4 waves
    int i;
    for (i = wv; i < jt; i += 4)
        attn_tile<false>(Kb, VT, Wpb, bh, hh, c, h5, 32 * i, t0A, qfA, Uw, OA, mA, lA);
    if (i == jt)
        attn_tile<true> (Kb, VT, Wpb, bh, hh, c, h5, 32 * i, t0A, qfA, Uw, OA, mA, lA);

    // state B: Q-tile 31-jt (32-jt s-tiles)
    const int jq2 = 31 - jt;
    for (i = wv; i < jq2; i += 4)
        attn_tile<false>(Kb, VT, Wpb, bh, hh, c, h5, 32 * i, t0B, qfB, Uw, OB, mB, lB);
    if (i == jq2)
        attn_tile<true> (Kb, VT, Wpb, bh, hh, c, h5, 32 * i, t0B, qfB, Uw, OB, mB, lB);

    // ---- cross-wave merge: partials -> LDS (reuse U_all) ----
    __syncthreads();
    float* Op = U_all;   // [qsel][wave][c][16]
    {
        int ba = ((0 * 4 + wv) * 32 + c) * 16;
        *(float4*)&Op[ba + 4 * h5]     = make_float4(OA[0], OA[1], OA[2], OA[3]);
        *(float4*)&Op[ba + 4 * h5 + 8] = make_float4(OA[4], OA[5], OA[6], OA[7]);
        int bb2 = ((1 * 4 + wv) * 32 + c) * 16;
        *(float4*)&Op[bb2 + 4 * h5]     = make_float4(OB[0], OB[1], OB[2], OB[3]);
        *(float4*)&Op[bb2 + 4 * h5 + 8] = make_float4(OB[4], OB[5], OB[6], OB[7]);
        if (h5 == 0) { mlb[0][wv][0][c] = mA; mlb[0][wv][1][c] = lA;
                       mlb[1][wv][0][c] = mB; mlb[1][wv][1][c] = lB; }
    }
    __syncthreads();
    if (wv < 2) {
        const int q = wv, t0q = q ? t0B : t0A;
        float mx = -1e30f;
        #pragma unroll
        for (int w = 0; w < 4; ++w) mx = fmaxf(mx, mlb[q][w][0][c]);
        float lt = 0.f;
        float a0=0, a1=0, a2=0, a3=0, b0=0, b1=0, b2=0, b3=0;
        #pragma unroll
        for (int w = 0; w < 4; ++w) {
            float fw = exp2f(mlb[q][w][0][c] - mx);
            lt += mlb[q][w][1][c] * fw;
            int ba = ((q * 4 + w) * 32 + c) * 16;
            float4 o1 = *(float4*)&Op[ba + 4 * h5];
            float4 o2 = *(float4*)&Op[ba + 4 * h5 + 8];
            a0 += o1.x * fw; a1 += o1.y * fw; a2 += o1.z * fw; a3 += o1.w * fw;
            b0 += o2.x * fw; b1 += o2.y * fw; b2 += o2.z * fw; b3 += o2.w * fw;
        }
        float inv = 1.f / lt;
        __hip_bfloat16* yp = yb + ((size_t)((bh >> 3) * T + t0q + c)) * C + (bh & 7) * E + 4 * h5;
        *(uint2*)yp       = make_uint2(pack2(a0 * inv, a1 * inv), pack2(a2 * inv, a3 * inv));
        *(uint2*)(yp + 8) = make_uint2(pack2(b0 * inv, b1 * inv), pack2(b2 * inv, b3 * inv));
    }
}

// ---------------- Kernel 3: output projection + residual via MFMA ----------------
__global__ __launch_bounds__(256) void k_proj(
    const __hip_bfloat16* __restrict__ yb, const __hip_bfloat16* __restrict__ WpT,
    const float* __restrict__ x, float* __restrict__ out)
{
    __shared__ ushort ylds[32 * 132];
    const int tid = threadIdx.x;
    const size_t row0 = (size_t)blockIdx.x * 32;

    #pragma unroll
    for (int ch = 0; ch < 2; ++ch) {
        int idx = tid + ch * 256;
        int r = idx >> 4, c8 = (idx & 15) * 8;
        const ushort* src = (const ushort*)yb + (row0 + r) * C + c8;
        uint4 a = *(const uint4*)src;
        *(uint2*)&ylds[r * 132 + c8]     = make_uint2(a.x, a.y);
        *(uint2*)&ylds[r * 132 + c8 + 4] = make_uint2(a.z, a.w);
    }
    __syncthreads();

    const int wv = tid >> 6, lane = tid & 63, c = lane & 31, h5 = lane >> 5;
    const int n0 = wv * 32;
    bf16x8 wf[8], yf[8];
    #pragma unroll
    for (int s = 0; s < 8; ++s)
        wf[s] = *(const bf16x8*)(WpT + (size_t)(n0 + c) * C + 16 * s + 8 * h5);
    #pragma unroll
    for (int s = 0; s < 8; ++s) {
        const ushort* lp = &ylds[c * 132 + 16 * s + 8 * h5];
        bf16x4 lo = *(const bf16x4*)lp;
        bf16x4 hi = *(const bf16x4*)(lp + 4);
        yf[s] = __builtin_shufflevector(lo, hi, 0, 1, 2, 3, 4, 5, 6, 7);
    }
    f32x16 acc;
    #pragma unroll
    for (int r = 0; r < 16; ++r) acc[r] = 0.f;
    #pragma unroll
    for (int s = 0; s < 8; ++s)
        acc = __builtin_amdgcn_mfma_f32_32x32x16_bf16(wf[s], yf[s], acc, 0, 0, 0);

    const size_t rb = (row0 + c) * C;
    #pragma unroll
    for (int j2 = 0; j2 < 4; ++j2) {
        int n = n0 + 4 * h5 + 8 * j2;
        float4 xr = *(const float4*)(x + rb + n);
        float4 o  = make_float4(acc[4*j2] + xr.x, acc[4*j2+1] + xr.y,
                                acc[4*j2+2] + xr.z, acc[4*j2+3] + xr.w);
        *(float4*)(out + rb + n) = o;
    }
}

extern "C" void kernel_launch(void* const* d_in, const int* in_sizes, int n_in,
                              void* d_out, int out_size, void* d_ws, size_t ws_size,
                              hipStream_t stream) {
    const float* x   = (const float*)d_in[0];
    const float* Wq  = (const float*)d_in[1];
    const float* Wk  = (const float*)d_in[2];
    const float* Wv  = (const float*)d_in[3];
    const float* Wp  = (const float*)d_in[4];
    const float* wpe = (const float*)d_in[5];
    const float* g   = (const float*)d_in[6];
    const float* bb  = (const float*)d_in[7];
    float* out = (float*)d_out;

    ushort* w = (ushort*)d_ws;
    __hip_bfloat16* Qb  = (__hip_bfloat16*)(w);                 // 1,048,576
    __hip_bfloat16* Kb  = (__hip_bfloat16*)(w + 1048576);       // 1,048,576
    __hip_bfloat16* VT  = (__hip_bfloat16*)(w + 2097152);       // 1,064,960 (+16 slack rows)
    __hip_bfloat16* Wpb = (__hip_bfloat16*)(w + 3162112);       //   131,200
    __hip_bfloat16* WT  = (__hip_bfloat16*)(w + 3293312);       //    49,152
    __hip_bfloat16* WpT = (__hip_bfloat16*)(w + 3342464);       //    16,384
    __hip_bfloat16* yb  = (__hip_bfloat16*)(w + 3358848);       // 1,048,576

    k_prep <<<1025 + 512, C,   0, stream>>>(wpe, Wq, Wk, Wv, Wp, Wpb, WT, WpT);
    k_qkv  <<<256,        256, 0, stream>>>(x, g, bb, WT, Qb, Kb, VT);
    k_attn <<<BH * 16,    256, 0, stream>>>(Qb, Kb, VT, Wpb, yb);
    k_proj <<<256,        256, 0, stream>>>(yb, WpT, x, out);
}

// Round 6
// 51.722 us; speedup vs baseline: 13.4905x; 1.1040x over previous
//
#include <hip/hip_runtime.h>
#include <hip/hip_bf16.h>

#define B 8
#define T 1024
#define C 128
#define H 8
#define E 16
#define BH (B*H)

typedef __attribute__((ext_vector_type(4)))  short bf16x4;
typedef __attribute__((ext_vector_type(8)))  short bf16x8;
typedef __attribute__((ext_vector_type(16))) float f32x16;

#define QSCALE 0.36067376022224085f   // 0.25 * log2(e): folds score scale + exp2 domain

__device__ __forceinline__ unsigned short bfbits(float x) {
    __hip_bfloat16 h = __float2bfloat16(x);
    return __builtin_bit_cast(unsigned short, h);
}
__device__ __forceinline__ unsigned pack2(float a, float b) {
    return (unsigned)bfbits(a) | ((unsigned)bfbits(b) << 16);
}
__device__ __forceinline__ float ubf(unsigned short u) {
    return __builtin_bit_cast(float, ((unsigned)u) << 16);
}

// ---------------- Kernel 0: prep — wpe per-head repack + weight transposes ----------------
__global__ __launch_bounds__(C) void k_prep(
    const float* __restrict__ wpe,
    const float* __restrict__ Wq, const float* __restrict__ Wk,
    const float* __restrict__ Wv, const float* __restrict__ Wp,
    __hip_bfloat16* __restrict__ Wpb,   // [H][1025][16]
    __hip_bfloat16* __restrict__ WT,    // [384][128]  rows: 0-127 Q(scaled), 128-255 K, 256-383 V
    __hip_bfloat16* __restrict__ WpT)   // [128][128]
{
    int bid = blockIdx.x, tid = threadIdx.x;
    if (bid < 1025) {
        int h = tid >> 4, e = tid & 15;
        Wpb[((size_t)h * 1025 + bid) * 16 + e] = __float2bfloat16(wpe[(size_t)bid * C + tid]);
    } else {
        int n = bid - 1025;   // 0..511
        if (n < 128)      WT[n * C + tid]          = __float2bfloat16(Wq[tid * C + n] * QSCALE);
        else if (n < 256) WT[n * C + tid]          = __float2bfloat16(Wk[tid * C + (n - 128)]);
        else if (n < 384) WT[n * C + tid]          = __float2bfloat16(Wv[tid * C + (n - 256)]);
        else              WpT[(n - 384) * C + tid] = __float2bfloat16(Wp[tid * C + (n - 384)]);
    }
}

// ---------------- Kernel 1: LayerNorm + QKV projection via MFMA ----------------
// grid 768 = 256 M-tiles x 3 parts (Q|K|V); block 256 = 4 waves, wave = 1 N-tile
__global__ __launch_bounds__(256) void k_qkv(
    const float* __restrict__ x, const float* __restrict__ g, const float* __restrict__ bb,
    const __hip_bfloat16* __restrict__ WT,
    __hip_bfloat16* __restrict__ Qb, __hip_bfloat16* __restrict__ Kb,
    __hip_bfloat16* __restrict__ VT)
{
    __shared__ ushort lnlds[32 * 132];
    const int tid = threadIdx.x;
    const int mt = blockIdx.x & 255, part = blockIdx.x >> 8;   // part 0:Q 1:K 2:V

    {   // LN phase: 8 threads per row
        const int r = tid >> 3, qq = tid & 7;
        const float* xp = x + ((size_t)mt * 32 + r) * C + qq * 16;
        float4 x0 = ((const float4*)xp)[0];
        float4 x1 = ((const float4*)xp)[1];
        float4 x2 = ((const float4*)xp)[2];
        float4 x3 = ((const float4*)xp)[3];
        float s1v = x0.x + x0.y + x0.z + x0.w + x1.x + x1.y + x1.z + x1.w
                  + x2.x + x2.y + x2.z + x2.w + x3.x + x3.y + x3.z + x3.w;
        float s2v = x0.x*x0.x + x0.y*x0.y + x0.z*x0.z + x0.w*x0.w
                  + x1.x*x1.x + x1.y*x1.y + x1.z*x1.z + x1.w*x1.w
                  + x2.x*x2.x + x2.y*x2.y + x2.z*x2.z + x2.w*x2.w
                  + x3.x*x3.x + x3.y*x3.y + x3.z*x3.z + x3.w*x3.w;
        s1v += __shfl_xor(s1v, 1, 64); s2v += __shfl_xor(s2v, 1, 64);
        s1v += __shfl_xor(s1v, 2, 64); s2v += __shfl_xor(s2v, 2, 64);
        s1v += __shfl_xor(s1v, 4, 64); s2v += __shfl_xor(s2v, 4, 64);
        float mu  = s1v * (1.f / C);
        float var = s2v * (1.f / C) - mu * mu;
        float rs  = rsqrtf(var + 1e-5f);
        const float4* gp = (const float4*)(g  + qq * 16);
        const float4* bp = (const float4*)(bb + qq * 16);
        float4 g0 = gp[0], g1 = gp[1], g2 = gp[2], g3 = gp[3];
        float4 b0 = bp[0], b1 = bp[1], b2 = bp[2], b3 = bp[3];
        #define LNV(xx, gg, bv) (((xx) - mu) * rs * (gg) + (bv))
        uint2* dst = (uint2*)&lnlds[r * 132 + qq * 16];
        dst[0] = make_uint2(pack2(LNV(x0.x,g0.x,b0.x), LNV(x0.y,g0.y,b0.y)),
                            pack2(LNV(x0.z,g0.z,b0.z), LNV(x0.w,g0.w,b0.w)));
        dst[1] = make_uint2(pack2(LNV(x1.x,g1.x,b1.x), LNV(x1.y,g1.y,b1.y)),
                            pack2(LNV(x1.z,g1.z,b1.z), LNV(x1.w,g1.w,b1.w)));
        dst[2] = make_uint2(pack2(LNV(x2.x,g2.x,b2.x), LNV(x2.y,g2.y,b2.y)),
                            pack2(LNV(x2.z,g2.z,b2.z), LNV(x2.w,g2.w,b2.w)));
        dst[3] = make_uint2(pack2(LNV(x3.x,g3.x,b3.x), LNV(x3.y,g3.y,b3.y)),
                            pack2(LNV(x3.z,g3.z,b3.z), LNV(x3.w,g3.w,b3.w)));
        #undef LNV
    }
    __syncthreads();

    const int wv = tid >> 6, lane = tid & 63, c = lane & 31, h5 = lane >> 5;
    const int b = mt >> 5, trow = (mt & 31) * 32;
    const int nt = part * 4 + wv, n0 = nt * 32;

    bf16x8 wf[8], lf[8];
    #pragma unroll
    for (int s = 0; s < 8; ++s)
        wf[s] = *(const bf16x8*)(WT + (size_t)(n0 + c) * C + 16 * s + 8 * h5);
    #pragma unroll
    for (int s = 0; s < 8; ++s) {
        const ushort* lp = &lnlds[c * 132 + 16 * s + 8 * h5];
        bf16x4 lo = *(const bf16x4*)lp;
        bf16x4 hi = *(const bf16x4*)(lp + 4);
        lf[s] = __builtin_shufflevector(lo, hi, 0, 1, 2, 3, 4, 5, 6, 7);
    }
    f32x16 acc;
    #pragma unroll
    for (int r = 0; r < 16; ++r) acc[r] = 0.f;

    if (nt < 8) {
        #pragma unroll
        for (int s = 0; s < 8; ++s)
            acc = __builtin_amdgcn_mfma_f32_32x32x16_bf16(wf[s], lf[s], acc, 0, 0, 0);
        __hip_bfloat16* base = (nt < 4) ? Qb : Kb;
        const int nb = (nt < 4 ? n0 : n0 - 128) + 4 * h5;
        #pragma unroll
        for (int j2 = 0; j2 < 4; ++j2) {
            int n = nb + 8 * j2;
            int h = n >> 4, e = n & 15;
            uint2 w = make_uint2(pack2(acc[4*j2], acc[4*j2+1]),
                                 pack2(acc[4*j2+2], acc[4*j2+3]));
            *(uint2*)(base + ((size_t)(b * H + h) * T + trow + c) * E + e) = w;
        }
    } else {
        #pragma unroll
        for (int s = 0; s < 8; ++s)
            acc = __builtin_amdgcn_mfma_f32_32x32x16_bf16(lf[s], wf[s], acc, 0, 0, 0);
        const int ecol = n0 - 256 + c;
        const int h = ecol >> 4, e = ecol & 15;
        __hip_bfloat16* vbase = VT + ((size_t)(b * H + h) * E + e) * T + trow + 4 * h5;
        #pragma unroll
        for (int j2 = 0; j2 < 4; ++j2) {
            uint2 w = make_uint2(pack2(acc[4*j2], acc[4*j2+1]),
                                 pack2(acc[4*j2+2], acc[4*j2+3]));
            *(uint2*)(vbase + 8 * j2) = w;
        }
    }
}

// ---------------- Kernel 2: MFMA flash attention, 1 Q-tile per block ----------------
template<bool DIAG>
__device__ __forceinline__ void attn_tile(
    const __hip_bfloat16* __restrict__ Kb, const __hip_bfloat16* __restrict__ VT,
    const __hip_bfloat16* __restrict__ Wpb,
    int bh, int hh, int c, int h5, int s0, int t0,
    const bf16x8 qf, ushort* __restrict__ Uw,
    f32x16& O, float& m, float& l)
{
    f32x16 Z;
    #pragma unroll
    for (int r = 0; r < 16; ++r) Z[r] = 0.f;

    const bf16x8 kf = *(const bf16x8*)(Kb + ((size_t)(bh * T + s0 + c) * E + 8 * h5));
    int dhi = t0 - s0 + c;
    int dlo = dhi - 32;
    if (DIAG) { if (dlo < 0) dlo = 0; }          // clamped rows feed masked entries only
    const bf16x8 wfh = *(const bf16x8*)(Wpb + ((size_t)(hh * 1025 + dhi) * E + 8 * h5));
    const bf16x8 wfl = *(const bf16x8*)(Wpb + ((size_t)(hh * 1025 + dlo) * E + 8 * h5));
    const bf16x8 va  = *(const bf16x8*)(VT + ((size_t)(bh * E + c) * T + s0 + 8 * h5));
    const bf16x8 vb  = *(const bf16x8*)(VT + ((size_t)(bh * E + c) * T + s0 + 16 + 8 * h5));

    f32x16 S   = __builtin_amdgcn_mfma_f32_32x32x16_bf16(kf,  qf, Z, 0, 0, 0);
    f32x16 Ulo = __builtin_amdgcn_mfma_f32_32x32x16_bf16(wfl, qf, Z, 0, 0, 0);
    f32x16 Uhi = __builtin_amdgcn_mfma_f32_32x32x16_bf16(wfh, qf, Z, 0, 0, 0);

    // U band -> LDS as bf16 [t=c][64], row stride 68 ushorts
    {
        ushort* up = Uw + c * 68 + 4 * h5;
        #pragma unroll
        for (int k2 = 0; k2 < 4; ++k2) {
            *(uint2*)(up + 8 * k2) =
                make_uint2(pack2(Ulo[4*k2], Ulo[4*k2+1]), pack2(Ulo[4*k2+2], Ulo[4*k2+3]));
            *(uint2*)(up + 32 + 8 * k2) =
                make_uint2(pack2(Uhi[4*k2], Uhi[4*k2+1]), pack2(Uhi[4*k2+2], Uhi[4*k2+3]));
        }
    }

    // diagonal gather + mask + online softmax (rows lane-local, exp2 domain)
    const ushort* ur = Uw + c * 68 + c + 32;
    float sc[16];
    float pmax = -1e30f;
    #pragma unroll
    for (int r = 0; r < 16; ++r) {
        const int rowm = 4 * h5 + (r & 3) + 8 * (r >> 2);
        float vv = S[r] + ubf(ur[-rowm]);
        if (DIAG) vv = (rowm <= c) ? vv : -1e30f;
        sc[r] = vv;
        pmax = fmaxf(pmax, vv);
    }
    pmax = fmaxf(pmax, __shfl_xor(pmax, 32, 64));
    const float mn = fmaxf(m, pmax);
    const float f = exp2f(m - mn);
    float ps = 0.f;
    float p[16];
    #pragma unroll
    for (int r = 0; r < 16; ++r) { p[r] = exp2f(sc[r] - mn); ps += p[r]; }
    ps += __shfl_xor(ps, 32, 64);
    l = l * f + ps;
    m = mn;
    #pragma unroll
    for (int r = 0; r < 8; ++r) O[r] *= f;

    // P -> bf16 B-fragments in-register (pack + cross-half shfl, no LDS)
    unsigned w0 = pack2(p[0], p[1]),  w1 = pack2(p[2], p[3]);
    unsigned w2 = pack2(p[4], p[5]),  w3 = pack2(p[6], p[7]);
    unsigned w4 = pack2(p[8], p[9]),  w5 = pack2(p[10], p[11]);
    unsigned w6 = pack2(p[12], p[13]), w7 = pack2(p[14], p[15]);
    unsigned r1 = __shfl_xor(h5 ? w0 : w2, 32, 64);
    unsigned r2 = __shfl_xor(h5 ? w1 : w3, 32, 64);
    unsigned r3 = __shfl_xor(h5 ? w4 : w6, 32, 64);
    unsigned r4 = __shfl_xor(h5 ? w5 : w7, 32, 64);
    uint4 f1 = h5 ? make_uint4(r1, r2, w2, w3) : make_uint4(w0, w1, r1, r2);
    uint4 f2 = h5 ? make_uint4(r3, r4, w6, w7) : make_uint4(w4, w5, r3, r4);
    bf16x8 pb1 = __builtin_bit_cast(bf16x8, f1);
    bf16x8 pb2 = __builtin_bit_cast(bf16x8, f2);

    O = __builtin_amdgcn_mfma_f32_32x32x16_bf16(va, pb1, O, 0, 0, 0);
    O = __builtin_amdgcn_mfma_f32_32x32x16_bf16(vb, pb2, O, 0, 0, 0);
}

// grid 2048 = 32 jq-ranks x 64 bh, heavy-first: jq = 31 - (bid>>6)
__global__ __launch_bounds__(256) void k_attn(
    const __hip_bfloat16* __restrict__ Qb, const __hip_bfloat16* __restrict__ Kb,
    const __hip_bfloat16* __restrict__ VT, const __hip_bfloat16* __restrict__ Wpb,
    __hip_bfloat16* __restrict__ yb)
{
    __shared__ __align__(16) ushort U_all[4][32 * 68];   // 17408 B; reused for O merge
    __shared__ float mlb[4][2][32];                       // 1 KB

    const int tid = threadIdx.x, wv = tid >> 6, lane = tid & 63;
    const int h5 = lane >> 5, c = lane & 31;
    const int bh = blockIdx.x & 63;
    const int jq = 31 - (blockIdx.x >> 6);
    const int hh = bh & (H - 1);
    const int t0 = jq << 5;
    ushort* Uw = U_all[wv];

    const bf16x8 qf = *(const bf16x8*)(Qb + ((size_t)(bh * T + t0 + c) * E + 8 * h5));

    f32x16 O;
    #pragma unroll
    for (int r = 0; r < 16; ++r) O[r] = 0.f;
    float m = -1e30f, l = 0.f;

    int i;
    for (i = wv; i < jq; i += 4)
        attn_tile<false>(Kb, VT, Wpb, bh, hh, c, h5, 32 * i, t0, qf, Uw, O, m, l);
    if (i == jq)
        attn_tile<true> (Kb, VT, Wpb, bh, hh, c, h5, 32 * i, t0, qf, Uw, O, m, l);

    // ---- cross-wave merge (reuse U_all as float [4][32][16]) ----
    __syncthreads();
    float* Of = (float*)&U_all[0][0];
    if (h5 == 0) { mlb[wv][0][c] = m; mlb[wv][1][c] = l; }
    float* ob = Of + (wv * 32 + c) * 16;
    *(float4*)(ob + 4 * h5)     = make_float4(O[0], O[1], O[2], O[3]);
    *(float4*)(ob + 4 * h5 + 8) = make_float4(O[4], O[5], O[6], O[7]);
    __syncthreads();
    if (wv == 0) {
        float mx = -1e30f;
        #pragma unroll
        for (int w = 0; w < 4; ++w) mx = fmaxf(mx, mlb[w][0][c]);
        float lt = 0.f;
        float a0=0, a1=0, a2=0, a3=0, b0=0, b1=0, b2=0, b3=0;
        #pragma unroll
        for (int w = 0; w < 4; ++w) {
            float fw = exp2f(mlb[w][0][c] - mx);
            lt += mlb[w][1][c] * fw;
            const float* op = Of + (w * 32 + c) * 16;
            float4 o1 = *(const float4*)(op + 4 * h5);
            float4 o2 = *(const float4*)(op + 4 * h5 + 8);
            a0 += o1.x * fw; a1 += o1.y * fw; a2 += o1.z * fw; a3 += o1.w * fw;
            b0 += o2.x * fw; b1 += o2.y * fw; b2 += o2.z * fw; b3 += o2.w * fw;
        }
        float inv = 1.f / lt;
        __hip_bfloat16* yp = yb + ((size_t)((bh >> 3) * T + t0 + c)) * C + (bh & 7) * E + 4 * h5;
        *(uint2*)yp       = make_uint2(pack2(a0 * inv, a1 * inv), pack2(a2 * inv, a3 * inv));
        *(uint2*)(yp + 8) = make_uint2(pack2(b0 * inv, b1 * inv), pack2(b2 * inv, b3 * inv));
    }
}

// ---------------- Kernel 3: output projection + residual via MFMA ----------------
__global__ __launch_bounds__(256) void k_proj(
    const __hip_bfloat16* __restrict__ yb, const __hip_bfloat16* __restrict__ WpT,
    const float* __restrict__ x, float* __restrict__ out)
{
    __shared__ ushort ylds[32 * 132];
    const int tid = threadIdx.x;
    const size_t row0 = (size_t)blockIdx.x * 32;

    #pragma unroll
    for (int ch = 0; ch < 2; ++ch) {
        int idx = tid + ch * 256;
        int r = idx >> 4, c8 = (idx & 15) * 8;
        const ushort* src = (const ushort*)yb + (row0 + r) * C + c8;
        uint4 a = *(const uint4*)src;
        *(uint2*)&ylds[r * 132 + c8]     = make_uint2(a.x, a.y);
        *(uint2*)&ylds[r * 132 + c8 + 4] = make_uint2(a.z, a.w);
    }
    __syncthreads();

    const int wv = tid >> 6, lane = tid & 63, c = lane & 31, h5 = lane >> 5;
    const int n0 = wv * 32;
    bf16x8 wf[8], yf[8];
    #pragma unroll
    for (int s = 0; s < 8; ++s)
        wf[s] = *(const bf16x8*)(WpT + (size_t)(n0 + c) * C + 16 * s + 8 * h5);
    #pragma unroll
    for (int s = 0; s < 8; ++s) {
        const ushort* lp = &ylds[c * 132 + 16 * s + 8 * h5];
        bf16x4 lo = *(const bf16x4*)lp;
        bf16x4 hi = *(const bf16x4*)(lp + 4);
        yf[s] = __builtin_shufflevector(lo, hi, 0, 1, 2, 3, 4, 5, 6, 7);
    }
    f32x16 acc;
    #pragma unroll
    for (int r = 0; r < 16; ++r) acc[r] = 0.f;
    #pragma unroll
    for (int s = 0; s < 8; ++s)
        acc = __builtin_amdgcn_mfma_f32_32x32x16_bf16(wf[s], yf[s], acc, 0, 0, 0);

    const size_t rb = (row0 + c) * C;
    #pragma unroll
    for (int j2 = 0; j2 < 4; ++j2) {
        int n = n0 + 4 * h5 + 8 * j2;
        float4 xr = *(const float4*)(x + rb + n);
        float4 o  = make_float4(acc[4*j2] + xr.x, acc[4*j2+1] + xr.y,
                                acc[4*j2+2] + xr.z, acc[4*j2+3] + xr.w);
        *(float4*)(out + rb + n) = o;
    }
}

extern "C" void kernel_launch(void* const* d_in, const int* in_sizes, int n_in,
                              void* d_out, int out_size, void* d_ws, size_t ws_size,
                              hipStream_t stream) {
    const float* x   = (const float*)d_in[0];
    const float* Wq  = (const float*)d_in[1];
    const float* Wk  = (const float*)d_in[2];
    const float* Wv  = (const float*)d_in[3];
    const float* Wp  = (const float*)d_in[4];
    const float* wpe = (const float*)d_in[5];
    const float* g   = (const float*)d_in[6];
    const float* bb  = (const float*)d_in[7];
    float* out = (float*)d_out;

    ushort* w = (ushort*)d_ws;
    __hip_bfloat16* Qb  = (__hip_bfloat16*)(w);                 // 1,048,576
    __hip_bfloat16* Kb  = (__hip_bfloat16*)(w + 1048576);       // 1,048,576
    __hip_bfloat16* VT  = (__hip_bfloat16*)(w + 2097152);       // 1,064,960 (+16 slack rows)
    __hip_bfloat16* Wpb = (__hip_bfloat16*)(w + 3162112);       //   131,200
    __hip_bfloat16* WT  = (__hip_bfloat16*)(w + 3293312);       //    49,152
    __hip_bfloat16* WpT = (__hip_bfloat16*)(w + 3342464);       //    16,384
    __hip_bfloat16* yb  = (__hip_bfloat16*)(w + 3358848);       // 1,048,576

    k_prep <<<1025 + 512, C,   0, stream>>>(wpe, Wq, Wk, Wv, Wp, Wpb, WT, WpT);
    k_qkv  <<<768,        256, 0, stream>>>(x, g, bb, WT, Qb, Kb, VT);
    k_attn <<<2048,       256, 0, stream>>>(Qb, Kb, VT, Wpb, yb);
    k_proj <<<256,        256, 0, stream>>>(yb, WpT, x, out);
}